// Round 1
// baseline (440.875 us; speedup 1.0000x reference)
//
#include <hip/hip_runtime.h>

// Problem constants (from reference setup_inputs)
#define BATCH 128
#define NPTS  4000          // N
#define NA    400           // N_A (knots = NA+1)
#define TPB   1024          // threads per block
#define KPT   4             // cells per thread
#define ACTIVE (NPTS / KPT) // 1000 active threads per block
#define BN    (BATCH * NPTS)

// f_real(u) = 0.5*u*(3-u^2) + 25*u^2*(0.75 - 2u + 1.5u^2 - 0.25u^4)
__device__ __forceinline__ float f_real(float u) {
    float u2 = u * u;
    float p  = 0.75f - 2.0f * u + 1.5f * u2 - 0.25f * u2 * u2;
    return 0.5f * u * (3.0f - u2) + 25.0f * u2 * p;
}

// |f'(u)| ; f'(u) = 1.5 + 37.5u - 151.5u^2 + 150u^3 - 37.5u^5
__device__ __forceinline__ float fprime_abs(float u) {
    float u2 = u * u;
    float v  = 1.5f + u * (37.5f + u * (-151.5f + u * (150.0f + u2 * (-37.5f))));
    return fabsf(v);
}

// jnp.interp(u, xp, Aa) with near-uniform knots: guessed index + small fixup.
__device__ __forceinline__ float interpA(float u, const float* __restrict__ xp,
                                         const float* __restrict__ Aa,
                                         const float* __restrict__ inv) {
    if (u <= xp[0])  return Aa[0];
    if (u >= xp[NA]) return Aa[NA];
    int j = (int)(u * (float)NA);
    j = j < 0 ? 0 : (j > NA - 1 ? NA - 1 : j);
    while (j > 0 && u < xp[j]) --j;
    while (j < NA - 1 && u >= xp[j + 1]) ++j;
    return Aa[j] + (Aa[j + 1] - Aa[j]) * ((u - xp[j]) * inv[j]);
}

__global__ __launch_bounds__(TPB)
void vclin_kernel(const float* __restrict__ init,
                  const float* __restrict__ u_a,
                  const float* __restrict__ dtp,
                  const float* __restrict__ dxp,
                  const int*   __restrict__ stepnump,
                  float* __restrict__ out) {
    // A(u) tables
    __shared__ float xp_s[NA + 1];
    __shared__ float Aa_s[NA + 1];
    __shared__ float inv_s[NA];
    // per-thread edge halos: first/last cell's (u, f, g, A)
    __shared__ float hUf[TPB], hFf[TPB], hGf[TPB], hAf[TPB]; // first cell of thread
    __shared__ float hUl[TPB], hFl[TPB], hGl[TPB], hAl[TPB]; // last  cell of thread

    const int t   = threadIdx.x;
    const int row = blockIdx.x;
    const float* ua_row = u_a + (size_t)row * (NA + 1);

    // ---- build A_a table faithfully from u_a (trapezoid cumsum) ----
    if (t <= NA) xp_s[t] = ua_row[t];
    __syncthreads();
    if (t < NA) {
        float du = xp_s[t + 1] - xp_s[t];
        inv_s[t] = 1.0f / du;
        float a0 = (xp_s[t]     < 0.5f) ? 0.0f : 0.5f;  // 0.5 * a_real
        float a1 = (xp_s[t + 1] < 0.5f) ? 0.0f : 0.5f;
        Aa_s[t + 1] = 0.5f * (a0 + a1) * du;            // segment area (temp)
    }
    __syncthreads();
    if (t == 0) {
        float acc = 0.0f;
        Aa_s[0] = 0.0f;
        for (int k = 1; k <= NA; ++k) { acc += Aa_s[k]; Aa_s[k] = acc; }
    }
    __syncthreads();

    const float DT    = dtp[0];
    const float DX    = dxp[0];
    const float lam   = DT / DX;
    const float invdx = 1.0f / DX;
    const int   steps = stepnump[0];

    const bool  active  = (t < ACTIVE);
    const size_t rowbase = (size_t)row * NPTS;

    float u0 = 0.f, u1 = 0.f, u2 = 0.f, u3 = 0.f;
    if (active) {
        float4 v = *reinterpret_cast<const float4*>(init + rowbase + 4 * t);
        u0 = v.x; u1 = v.y; u2 = v.z; u3 = v.w;
        *reinterpret_cast<float4*>(out + rowbase + 4 * t) = v;   // trajectory step 0 = init
    }

    for (int s = 0; s < steps; ++s) {
        float f0, f1, f2, f3, g0, g1, g2, g3, A0, A1, A2, A3;
        if (active) {
            f0 = f_real(u0); f1 = f_real(u1); f2 = f_real(u2); f3 = f_real(u3);
            g0 = fprime_abs(u0); g1 = fprime_abs(u1); g2 = fprime_abs(u2); g3 = fprime_abs(u3);
            A0 = interpA(u0, xp_s, Aa_s, inv_s);
            A1 = interpA(u1, xp_s, Aa_s, inv_s);
            A2 = interpA(u2, xp_s, Aa_s, inv_s);
            A3 = interpA(u3, xp_s, Aa_s, inv_s);
            hUf[t] = u0; hFf[t] = f0; hGf[t] = g0; hAf[t] = A0;
            hUl[t] = u3; hFl[t] = f3; hGl[t] = g3; hAl[t] = A3;
        }
        __syncthreads();

        float nu0 = 0.f, nu1 = 0.f, nu2 = 0.f, nu3 = 0.f;
        if (active) {
            float lu = 0.f, lf = 0.f, lg = 0.f, la = 0.f;
            float ru = 0.f, rf = 0.f, rg = 0.f, ra = 0.f;
            if (t > 0)          { lu = hUl[t - 1]; lf = hFl[t - 1]; lg = hGl[t - 1]; la = hAl[t - 1]; }
            if (t < ACTIVE - 1) { ru = hUf[t + 1]; rf = hFf[t + 1]; rg = hGf[t + 1]; ra = hAf[t + 1]; }

            // interfaces: fh[m] sits between cell (m-1) and cell m of this thread's chunk
            float fh0 = 0.5f * (lf + f0) - 0.5f * fmaxf(lg, g0) * (u0 - lu);
            float fh1 = 0.5f * (f0 + f1) - 0.5f * fmaxf(g0, g1) * (u1 - u0);
            float fh2 = 0.5f * (f1 + f2) - 0.5f * fmaxf(g1, g2) * (u2 - u1);
            float fh3 = 0.5f * (f2 + f3) - 0.5f * fmaxf(g2, g3) * (u3 - u2);
            float fh4 = 0.5f * (f3 + rf) - 0.5f * fmaxf(g3, rg) * (ru - u3);

            float Ah0 = (A0 - la) * invdx;
            float Ah1 = (A1 - A0) * invdx;
            float Ah2 = (A2 - A1) * invdx;
            float Ah3 = (A3 - A2) * invdx;
            float Ah4 = (ra - A3) * invdx;

            nu0 = u0 - lam * (fh1 - fh0) + lam * (Ah1 - Ah0);
            nu1 = u1 - lam * (fh2 - fh1) + lam * (Ah2 - Ah1);
            nu2 = u2 - lam * (fh3 - fh2) + lam * (Ah3 - Ah2);
            nu3 = u3 - lam * (fh4 - fh3) + lam * (Ah4 - Ah3);

            // boundary: u_new[0] = u_new[1]; u_new[N-1] = u_new[N-2]
            if (t == 0)          nu0 = nu1;
            if (t == ACTIVE - 1) nu3 = nu2;
        }
        __syncthreads();   // protects halo arrays for next step's writes

        if (active) {
            u0 = nu0; u1 = nu1; u2 = nu2; u3 = nu3;
            float4 v; v.x = u0; v.y = u1; v.z = u2; v.w = u3;
            *reinterpret_cast<float4*>(out + (size_t)(s + 1) * BN + rowbase + 4 * t) = v;
        }
    }
}

extern "C" void kernel_launch(void* const* d_in, const int* in_sizes, int n_in,
                              void* d_out, int out_size, void* d_ws, size_t ws_size,
                              hipStream_t stream) {
    const float* init     = (const float*)d_in[0];   // (128, 4000)
    const float* u_a      = (const float*)d_in[1];   // (128, 401)
    const float* dt       = (const float*)d_in[2];   // (1,)
    const float* dx       = (const float*)d_in[3];   // (1,)
    const int*   stepnum  = (const int*)  d_in[4];   // scalar -> 1-elem int array
    float* out = (float*)d_out;                      // (101, 128, 4000) fp32

    hipLaunchKernelGGL(vclin_kernel, dim3(BATCH), dim3(TPB), 0, stream,
                       init, u_a, dt, dx, stepnum, out);
}

// Round 2
// 281.421 us; speedup vs baseline: 1.5666x; 1.5666x over previous
//
#include <hip/hip_runtime.h>

// ---- problem constants (reference setup_inputs) ----
#define BATCH  128
#define NPTS   4000
#define NA     400
#define BN     (BATCH * NPTS)

// ---- decomposition ----
// 4 chunks/row x 1000 cells, halo 52 each side, 50 steps/launch, 2 launches.
// Validity: halo cell j (local) is corrupt at step >= j+1; owned region starts
// at local 52 > 50 steps -> never contaminated. True BC applied at g==0/3999.
#define CHUNKS 4
#define CHUNK  (NPTS / CHUNKS)     // 1000
#define SSTEPS 50                  // steps per launch
#define HALO   52                  // >= SSTEPS+2, multiple of 4 (alignment)
#define LLEN   (CHUNK + 2 * HALO)  // 1104 local cells
#define NACT   (LLEN / 4)          // 276 active threads (4 cells each)
#define TPB    320                 // 5 waves; grid 512 = 2 blocks/CU -> 10 waves/CU

// f(u) = 0.5u(3-u^2) + 25u^2(0.75 - 2u + 1.5u^2 - 0.25u^4)
__device__ __forceinline__ float f_real(float u) {
    float u2 = u * u;
    float p  = fmaf(u2, fmaf(u2, -0.25f, 1.5f), fmaf(u, -2.0f, 0.75f));
    return u * fmaf(u2, -0.5f, 1.5f) + 25.0f * u2 * p;
}

// f'(u) = 1.5 + 37.5u - 151.5u^2 + 150u^3 - 37.5u^5  (signed; abs folded by caller)
__device__ __forceinline__ float fprime(float u) {
    float u2 = u * u;
    return fmaf(u, fmaf(u, fmaf(u, fmaf(u2, -37.5f, 150.0f), -151.5f), 37.5f), 1.5f);
}

// Closed-form A(u): trapz-cumsum of 0.5*step(u>=0.5) over knots is piecewise
// linear, slopes {0, 0.25, 0.5}, capped at Amax. Convex -> max of lines.
__device__ __forceinline__ float A_of_u(float u, float xlo, float xhi,
                                        float Aj0, float Amax) {
    float m = fmaxf(0.25f * (u - xlo), fmaf(0.5f, u - xhi, Aj0));
    m = fmaxf(m, 0.0f);
    return fminf(m, Amax);
}

__device__ __forceinline__ int iclamp(int v, int lo, int hi) {
    return v < lo ? lo : (v > hi ? hi : v);
}

__global__ __launch_bounds__(TPB)
void vclin_step_kernel(const float* __restrict__ src,   // state at step0 (B x N)
                       float* __restrict__ out,          // traj base (101 x B x N)
                       const float* __restrict__ u_a,
                       const float* __restrict__ dtp,
                       const float* __restrict__ dxp,
                       int step0, int write_src) {
    __shared__ float hL[2][TPB];   // first cell of each thread (parity-buffered)
    __shared__ float hR[2][TPB];   // last  cell of each thread
    __shared__ float tbl[3];       // xlo, xhi, xmax

    const int t     = threadIdx.x;
    const int row   = blockIdx.x >> 2;       // CHUNKS = 4
    const int chunk = blockIdx.x & 3;
    const int own_start = chunk * CHUNK;
    const int ls    = own_start - HALO;      // local 0 <-> global ls (may be <0)
    const int gbase = ls + 4 * t;            // global idx of this thread's cell 0
    const bool active = (t < NACT);
    const bool owner  = active && gbase >= own_start && gbase < own_start + CHUNK;
    const size_t rowbase = (size_t)row * NPTS;

    // ---- locate the 0.5 step in the actual u_a knots (once per launch) ----
    const float* ua_row = u_a + (size_t)row * (NA + 1);
    for (int k = t + 1; k <= NA; k += TPB) {
        float a = ua_row[k - 1], b = ua_row[k];
        if (a < 0.5f && b >= 0.5f) { tbl[0] = a; tbl[1] = b; tbl[2] = ua_row[NA]; }
    }

    const float DT  = dtp[0];
    const float DX  = dxp[0];
    const float lam = DT / DX;
    const float invdx = 1.0f / DX;

    // ---- load local state (clamped at row ends for virtual/edge cells) ----
    float u0 = 0.f, u1 = 0.f, u2 = 0.f, u3 = 0.f;
    if (active) {
        if (gbase >= 0 && gbase + 3 < NPTS) {
            float4 v = *reinterpret_cast<const float4*>(src + rowbase + gbase);
            u0 = v.x; u1 = v.y; u2 = v.z; u3 = v.w;
        } else {
            u0 = src[rowbase + iclamp(gbase,     0, NPTS - 1)];
            u1 = src[rowbase + iclamp(gbase + 1, 0, NPTS - 1)];
            u2 = src[rowbase + iclamp(gbase + 2, 0, NPTS - 1)];
            u3 = src[rowbase + iclamp(gbase + 3, 0, NPTS - 1)];
        }
    }

    __syncthreads();
    const float xlo  = tbl[0];
    const float xhi  = tbl[1];
    const float Aj0  = 0.25f * (xhi - xlo);
    const float Amax = fmaf(0.5f, tbl[2] - xhi, Aj0);

    float* wp = nullptr;
    if (owner) {
        wp = out + (size_t)(step0 + 1) * BN + rowbase + gbase;
        if (write_src) {   // trajectory step 0 = init (only first launch)
            float4 v; v.x = u0; v.y = u1; v.z = u2; v.w = u3;
            *reinterpret_cast<float4*>(out + rowbase + gbase) = v;
        }
    }

    for (int s = 0; s < SSTEPS; ++s) {
        const int p = s & 1;
        float f0, f1, f2, f3, g0, g1, g2, g3, A0, A1, A2, A3;
        if (active) {
            hL[p][t] = u0; hR[p][t] = u3;          // publish halos first
            f0 = f_real(u0); f1 = f_real(u1); f2 = f_real(u2); f3 = f_real(u3);
            g0 = fabsf(fprime(u0)); g1 = fabsf(fprime(u1));
            g2 = fabsf(fprime(u2)); g3 = fabsf(fprime(u3));
            A0 = A_of_u(u0, xlo, xhi, Aj0, Amax);
            A1 = A_of_u(u1, xlo, xhi, Aj0, Amax);
            A2 = A_of_u(u2, xlo, xhi, Aj0, Amax);
            A3 = A_of_u(u3, xlo, xhi, Aj0, Amax);
        }
        __syncthreads();                            // single barrier per step
        if (active) {
            float lu = (t > 0)        ? hR[p][t - 1] : u0;   // self-clamp at local ends:
            float ru = (t < NACT - 1) ? hL[p][t + 1] : u3;   // only corrupts invalid zone
            float lf = f_real(lu), lg = fabsf(fprime(lu));
            float la = A_of_u(lu, xlo, xhi, Aj0, Amax);
            float rf = f_real(ru), rg = fabsf(fprime(ru));
            float ra = A_of_u(ru, xlo, xhi, Aj0, Amax);

            // interface flux F = 0.5(f_l+f_r) - 0.5*max(g_l,g_r)*(u_r-u_l) - (A_r-A_l)/dx
            float F0 = 0.5f * (lf + f0) - 0.5f * fmaxf(lg, g0) * (u0 - lu) - invdx * (A0 - la);
            float F1 = 0.5f * (f0 + f1) - 0.5f * fmaxf(g0, g1) * (u1 - u0) - invdx * (A1 - A0);
            float F2 = 0.5f * (f1 + f2) - 0.5f * fmaxf(g1, g2) * (u2 - u1) - invdx * (A2 - A1);
            float F3 = 0.5f * (f2 + f3) - 0.5f * fmaxf(g2, g3) * (u3 - u2) - invdx * (A3 - A2);
            float F4 = 0.5f * (f3 + rf) - 0.5f * fmaxf(g3, rg) * (ru - u3) - invdx * (ra - A3);

            float nu0 = fmaf(-lam, F1 - F0, u0);
            float nu1 = fmaf(-lam, F2 - F1, u1);
            float nu2 = fmaf(-lam, F3 - F2, u2);
            float nu3 = fmaf(-lam, F4 - F3, u3);

            // true boundary: u[0] = u_new[1]; u[N-1] = u_new[N-2]
            if (gbase == 0)        nu0 = nu1;
            if (gbase == NPTS - 4) nu3 = nu2;

            u0 = nu0; u1 = nu1; u2 = nu2; u3 = nu3;
            if (owner) {
                float4 v; v.x = u0; v.y = u1; v.z = u2; v.w = u3;
                *reinterpret_cast<float4*>(wp) = v;
                wp += BN;
            }
        }
    }
}

extern "C" void kernel_launch(void* const* d_in, const int* in_sizes, int n_in,
                              void* d_out, int out_size, void* d_ws, size_t ws_size,
                              hipStream_t stream) {
    const float* init = (const float*)d_in[0];   // (128, 4000)
    const float* u_a  = (const float*)d_in[1];   // (128, 401)
    const float* dt   = (const float*)d_in[2];
    const float* dx   = (const float*)d_in[3];
    float* out = (float*)d_out;                  // (101, 128, 4000) fp32

    const int grid = BATCH * CHUNKS;             // 512 blocks = 2 per CU

    // steps 1..50 from init (also writes step 0)
    hipLaunchKernelGGL(vclin_step_kernel, dim3(grid), dim3(TPB), 0, stream,
                       init, out, u_a, dt, dx, 0, 1);
    // steps 51..100 from out[50]
    hipLaunchKernelGGL(vclin_step_kernel, dim3(grid), dim3(TPB), 0, stream,
                       out + (size_t)SSTEPS * BN, out, u_a, dt, dx, SSTEPS, 0);
}

// Round 3
// 264.651 us; speedup vs baseline: 1.6659x; 1.0634x over previous
//
#include <hip/hip_runtime.h>

// ---- problem constants (reference setup_inputs) ----
#define BATCH  128
#define NPTS   4000
#define NA     400
#define BN     (BATCH * NPTS)

// ---- wave-independent decomposition ----
// 10 waves per row; each wave owns 400 cells, plus 56-cell halo each side:
// 512 local cells = 8 per lane. Halo 56 > 50 steps + margin -> owned region
// never contaminated by the lane-edge self-clamp. NO __syncthreads anywhere;
// neighbor exchange is intra-wave __shfl. 2 launches x 50 steps.
#define CHUNKS 10
#define OWN    (NPTS / CHUNKS)   // 400
#define HALO   56
#define CPL    8                 // cells per lane
#define SSTEPS 50

// f(u) = 0.5u(3-u^2) + 25u^2(0.75 - 2u + 1.5u^2 - 0.25u^4)
__device__ __forceinline__ float f_real(float u) {
    float u2 = u * u;
    float p  = fmaf(u2, fmaf(u2, -0.25f, 1.5f), fmaf(u, -2.0f, 0.75f));
    return u * fmaf(u2, -0.5f, 1.5f) + 25.0f * u2 * p;
}

// |f'(u)|; f'(u) = 1.5 + 37.5u - 151.5u^2 + 150u^3 - 37.5u^5
__device__ __forceinline__ float fprime_abs(float u) {
    float u2 = u * u;
    return fabsf(fmaf(u, fmaf(u, fmaf(u, fmaf(u2, -37.5f, 150.0f), -151.5f), 37.5f), 1.5f));
}

// Closed-form A(u): piecewise linear, slopes {0, .25, .5}, capped. Convex.
__device__ __forceinline__ float A_of_u(float u, float xlo, float xhi,
                                        float Aj0, float Amax) {
    float m = fmaxf(0.25f * (u - xlo), fmaf(0.5f, u - xhi, Aj0));
    return fminf(fmaxf(m, 0.0f), Amax);
}

__device__ __forceinline__ int iclamp(int v, int lo, int hi) {
    return v < lo ? lo : (v > hi ? hi : v);
}

__global__ __launch_bounds__(64)
void vclin_wave_kernel(const float* __restrict__ src,   // state at step0 (B x N)
                       float* __restrict__ out,          // traj base (101 x B x N)
                       const float* __restrict__ u_a,
                       const float* __restrict__ dtp,
                       const float* __restrict__ dxp,
                       int step0, int write_src) {
    const int lane  = threadIdx.x;            // 0..63 (one wave per block)
    const int w     = blockIdx.x;
    const int row   = w / CHUNKS;
    const int chunk = w - row * CHUNKS;
    const int own_start = chunk * OWN;
    const int gbase = own_start - HALO + CPL * lane;     // global idx of cell 0
    const bool owner = (gbase >= own_start) && (gbase < own_start + OWN);
    const size_t rowbase = (size_t)row * NPTS;

    // ---- locate the 0.5 step in this row's u_a knots (wave-local, no LDS) ----
    const float* ua_row = u_a + (size_t)row * (NA + 1);
    float xlo = 0.0f, xhi = 1.0f;
    bool found = false;
    #pragma unroll
    for (int j = 0; j < 7; ++j) {
        int k = 7 * lane + j;
        if (k < NA) {
            float a = ua_row[k], b = ua_row[k + 1];
            if (a < 0.5f && b >= 0.5f) { xlo = a; xhi = b; found = true; }
        }
    }
    unsigned long long m = __ballot(found);
    int srcLane = (m != 0ull) ? (__ffsll((long long)m) - 1) : 0;
    xlo = __shfl(xlo, srcLane);
    xhi = __shfl(xhi, srcLane);
    const float xmax = ua_row[NA];
    const float Aj0  = 0.25f * (xhi - xlo);
    const float Amax = fmaf(0.5f, xmax - xhi, Aj0);

    const float DT  = dtp[0];
    const float DX  = dxp[0];
    const float lam = DT / DX;
    const float invdx = 1.0f / DX;

    // ---- load 8 local cells (clamped at row ends for virtual cells) ----
    float u[CPL];
    if (gbase >= 0 && gbase + CPL <= NPTS) {
        float4 a = *reinterpret_cast<const float4*>(src + rowbase + gbase);
        float4 b = *reinterpret_cast<const float4*>(src + rowbase + gbase + 4);
        u[0] = a.x; u[1] = a.y; u[2] = a.z; u[3] = a.w;
        u[4] = b.x; u[5] = b.y; u[6] = b.z; u[7] = b.w;
    } else {
        #pragma unroll
        for (int c = 0; c < CPL; ++c)
            u[c] = src[rowbase + iclamp(gbase + c, 0, NPTS - 1)];
    }

    float* wp = nullptr;
    if (owner) {
        wp = out + (size_t)(step0 + 1) * BN + rowbase + gbase;
        if (write_src) {   // first launch also writes trajectory step 0 = init
            float4 a; a.x = u[0]; a.y = u[1]; a.z = u[2]; a.w = u[3];
            float4 b; b.x = u[4]; b.y = u[5]; b.z = u[6]; b.w = u[7];
            *reinterpret_cast<float4*>(out + rowbase + gbase)     = a;
            *reinterpret_cast<float4*>(out + rowbase + gbase + 4) = b;
        }
    }

    const bool bcL = (gbase == 0);
    const bool bcR = (gbase == NPTS - CPL);

    for (int s = 0; s < SSTEPS; ++s) {
        float f[CPL], g[CPL], A[CPL];
        #pragma unroll
        for (int c = 0; c < CPL; ++c) {
            f[c] = f_real(u[c]);
            g[c] = fprime_abs(u[c]);
            A[c] = A_of_u(u[c], xlo, xhi, Aj0, Amax);
        }

        // neighbor edge cells via intra-wave shuffle (issued early, used late)
        float lu = __shfl_up(u[CPL - 1], 1);
        float lf = __shfl_up(f[CPL - 1], 1);
        float lg = __shfl_up(g[CPL - 1], 1);
        float lA = __shfl_up(A[CPL - 1], 1);
        float ru = __shfl_down(u[0], 1);
        float rf = __shfl_down(f[0], 1);
        float rg = __shfl_down(g[0], 1);
        float rA = __shfl_down(A[0], 1);
        if (lane == 0)  { lu = u[0]; lf = f[0]; lg = g[0]; lA = A[0]; }         // self-clamp:
        if (lane == 63) { ru = u[CPL-1]; rf = f[CPL-1]; rg = g[CPL-1]; rA = A[CPL-1]; } // corrupts only halo zone

        // interface flux F = 0.5(f_l+f_r) - 0.5*max(g_l,g_r)*(u_r-u_l) - (A_r-A_l)/dx
        float F[CPL + 1];
        F[0] = 0.5f * (lf + f[0]) - 0.5f * fmaxf(lg, g[0]) * (u[0] - lu) - invdx * (A[0] - lA);
        #pragma unroll
        for (int c = 1; c < CPL; ++c)
            F[c] = 0.5f * (f[c-1] + f[c]) - 0.5f * fmaxf(g[c-1], g[c]) * (u[c] - u[c-1])
                 - invdx * (A[c] - A[c-1]);
        F[CPL] = 0.5f * (f[CPL-1] + rf) - 0.5f * fmaxf(g[CPL-1], rg) * (ru - u[CPL-1])
               - invdx * (rA - A[CPL-1]);

        float nu[CPL];
        #pragma unroll
        for (int c = 0; c < CPL; ++c)
            nu[c] = fmaf(-lam, F[c + 1] - F[c], u[c]);

        // true boundary: u[0] = u_new[1]; u[N-1] = u_new[N-2]
        if (bcL) nu[0] = nu[1];
        if (bcR) nu[CPL - 1] = nu[CPL - 2];

        #pragma unroll
        for (int c = 0; c < CPL; ++c) u[c] = nu[c];

        if (owner) {
            float4 a; a.x = u[0]; a.y = u[1]; a.z = u[2]; a.w = u[3];
            float4 b; b.x = u[4]; b.y = u[5]; b.z = u[6]; b.w = u[7];
            *reinterpret_cast<float4*>(wp)     = a;
            *reinterpret_cast<float4*>(wp + 4) = b;
            wp += BN;
        }
    }
}

extern "C" void kernel_launch(void* const* d_in, const int* in_sizes, int n_in,
                              void* d_out, int out_size, void* d_ws, size_t ws_size,
                              hipStream_t stream) {
    const float* init = (const float*)d_in[0];   // (128, 4000)
    const float* u_a  = (const float*)d_in[1];   // (128, 401)
    const float* dt   = (const float*)d_in[2];
    const float* dx   = (const float*)d_in[3];
    float* out = (float*)d_out;                  // (101, 128, 4000) fp32

    const int grid = BATCH * CHUNKS;             // 1280 single-wave blocks

    // steps 1..50 from init (also writes step 0)
    hipLaunchKernelGGL(vclin_wave_kernel, dim3(grid), dim3(64), 0, stream,
                       init, out, u_a, dt, dx, 0, 1);
    // steps 51..100 from out[50]
    hipLaunchKernelGGL(vclin_wave_kernel, dim3(grid), dim3(64), 0, stream,
                       out + (size_t)SSTEPS * BN, out, u_a, dt, dx, SSTEPS, 0);
}